// Round 3
// baseline (587.027 us; speedup 1.0000x reference)
//
#include <hip/hip_runtime.h>
#include <stdint.h>

#define DEVI __device__ __forceinline__

using bf16x8 = __attribute__((ext_vector_type(8))) __bf16;
using f32x4  = __attribute__((ext_vector_type(4))) float;

DEVI ushort f2bf(float f){
  uint32_t u = __float_as_uint(f);
  uint32_t r = u + 0x7fffu + ((u >> 16) & 1u);   // RNE
  return (ushort)(r >> 16);
}
DEVI float bf2f(ushort h){ return __uint_as_float(((uint32_t)h) << 16); }

// async 16B global -> LDS (wave-uniform LDS base; lane lands at base + lane*16)
DEVI void async16(const ushort* g, ushort* l, int lbyte) {
  __builtin_amdgcn_global_load_lds(
      (const __attribute__((address_space(1))) uint32_t*)g,
      (__attribute__((address_space(3))) uint32_t*)((char*)l + lbyte),
      16, 0, 0);
}

// ---------------------------------------------------------------------------
// Segmented mega kernel. Paths:
//  flags&128: FUSED GCN LAYER  out = relu(G @ (X @ Wslab)) [+ dual branch]
//             block = (z, 64-col slab). REG-DIRECT operands: A/B fragments
//             loaded straight from global (L2-resident; XCD swizzle keeps
//             same-z blocks on one XCD). NO K-loop barriers, no staging LDS.
//             LDS holds only Yt (phase1 output, transposed, consumed as the
//             phase2 B operand). 4 barriers/block total (around Yt dump).
//  flags&64 : fused Sc + row softmax (LDS-staged, pipelined — unchanged)
//  else     : plain NT GEMM 128x128 tile, reg-direct, barrier-free
// flags: 1=relu 2=out_bf16 4=add Src2 bf16 16=dual 64=ScS 128=fused layer
// ---------------------------------------------------------------------------
struct Seg {
  const ushort* A; const ushort* B; const void* Src; const void* Src2; void* O;
  long long sA, sB, sS, sS2, sO;
  int lda, ldb, ldS, ldS2, ldc;
  int K, nbx, nbxy, flags;
  long long A2off, B2off;
};

__global__ __launch_bounds__(256, 2)
void mega(Seg s0, Seg s1, Seg s2, int n0s, int n01)
{
  extern __shared__ __align__(16) ushort lds[];
  int bid = blockIdx.x;
  const Seg& s = (bid < n0s) ? s0 : ((bid < n01) ? s1 : s2);
  if (bid >= n0s) bid -= (bid < n01) ? n0s : n01;

  const int t = threadIdx.x;
  const int lane = t & 63, wave = t >> 6;
  const int lr = lane & 15, lq = lane >> 4;
  const int lb0 = __builtin_amdgcn_readfirstlane((t & 192) * 16);

#define MFMA16(Aa, Bb) { _Pragma("unroll") for (int x = 0; x < 4; x++)           \
    _Pragma("unroll") for (int y = 0; y < 4; y++)                                \
      acc[x][y] = __builtin_amdgcn_mfma_f32_16x16x32_bf16(Aa[x], Bb[y], acc[x][y], 0, 0, 0); }

  if (s.flags & 128) {
    // ================= fused GCN layer (reg-direct) =================
    const int z    = (bid & 7) + ((bid >> 6) << 3);   // XCD swizzle: same z -> same XCD
    const int slab = (bid >> 3) & 7;
    const int n0   = slab * 64;

    ushort* Yt = lds;   // 64 cols x 264 (256 rows + pad), bf16

    const ushort* X  = s.A + (long long)z * s.sA;
    const ushort* Wf = s.B + (long long)n0 * 512;
    const ushort* G0 = (const ushort*)s.Src + (long long)z * s.sS;

    f32x4 acc[4][4] = {};
    uint pk[4][4][2];
    const int npass = (s.flags & 16) ? 2 : 1;

    const int arow = 64*wave + lr;    // fragment row base (+x*16)

    for (int p = 0; p < npass; ++p) {
      const ushort* Wp = p ? (Wf + s.B2off) : Wf;
      const ushort* Gp = p ? (G0 + s.A2off) : G0;

      // ---- phase 1: Y(256x64) = X @ Wslab  (K=512), barrier-free ----
      {
        const ushort* pX = X  + (long long)arow * 512 + lq*8;  // +x*16*512
        const ushort* pW = Wp + (long long)lr   * 512 + lq*8;  // +y*16*512
        #pragma unroll 4
        for (int k0 = 0; k0 < 512; k0 += 32) {
          bf16x8 af[4], bw[4];
          #pragma unroll
          for (int x = 0; x < 4; x++) af[x] = *(const bf16x8*)(pX + x*8192 + k0);
          #pragma unroll
          for (int y = 0; y < 4; y++) bw[y] = *(const bf16x8*)(pW + y*8192 + k0);
          MFMA16(af, bw);
        }
      }
      __syncthreads();   // prior pass's Yt reads complete before overwrite
      // dump Y -> Yt transposed (bf16), reset acc
      #pragma unroll
      for (int x = 0; x < 4; x++)
        #pragma unroll
        for (int y = 0; y < 4; y++) {
          const int col  = y*16 + lr;
          const int rowb = 64*wave + x*16 + lq*4;
          uint2 v;
          v.x = (uint)f2bf(acc[x][y][0]) | ((uint)f2bf(acc[x][y][1]) << 16);
          v.y = (uint)f2bf(acc[x][y][2]) | ((uint)f2bf(acc[x][y][3]) << 16);
          *(uint2*)&Yt[col*264 + rowb] = v;
          acc[x][y] = (f32x4){0.f, 0.f, 0.f, 0.f};
        }
      __syncthreads();   // Yt ready
      // ---- phase 2: acc = G(256x256) @ Y, barrier-free (Yt read-only) ----
      {
        const ushort* pG = Gp + (long long)arow * 256 + lq*8;  // ldS==256; +x*16*256
        #pragma unroll 4
        for (int k0 = 0; k0 < 256; k0 += 32) {
          bf16x8 af[4], bfr[4];
          #pragma unroll
          for (int x = 0; x < 4; x++) af[x] = *(const bf16x8*)(pG + x*4096 + k0);
          #pragma unroll
          for (int y = 0; y < 4; y++) bfr[y] = *(const bf16x8*)&Yt[(y*16 + lr)*264 + k0 + lq*8];
          MFMA16(af, bfr);
        }
      }
      if (p == 0 && npass == 2) {   // stash relu(forward branch) packed bf16
        #pragma unroll
        for (int x = 0; x < 4; x++)
          #pragma unroll
          for (int y = 0; y < 4; y++) {
            pk[x][y][0] = (uint)f2bf(fmaxf(acc[x][y][0],0.f)) | ((uint)f2bf(fmaxf(acc[x][y][1],0.f)) << 16);
            pk[x][y][1] = (uint)f2bf(fmaxf(acc[x][y][2],0.f)) | ((uint)f2bf(fmaxf(acc[x][y][3],0.f)) << 16);
            acc[x][y] = (f32x4){0.f, 0.f, 0.f, 0.f};
          }
      }
    }
    // epilogue: row = 64*wave + x*16 + lq*4 + r, col = n0 + y*16 + lr
    const int fl = s.flags;
    #pragma unroll
    for (int x = 0; x < 4; x++)
      #pragma unroll
      for (int y = 0; y < 4; y++) {
        const int col = n0 + y*16 + lr;
        #pragma unroll
        for (int r = 0; r < 4; r++) {
          const int row = 64*wave + x*16 + lq*4 + r;
          float v = fmaxf(acc[x][y][r], 0.f);
          if (fl & 16) v += bf2f((ushort)(pk[x][y][r >> 1] >> (16*(r & 1))));
          if (fl & 4)  v += bf2f(((const ushort*)s.Src2)[(long long)z*s.sS2 + (long long)row*s.ldS2 + col]);
          if (fl & 2)
            ((ushort*)s.O)[(long long)z*s.sO + (long long)row*s.ldc + col] = f2bf(v);
          else
            ((float*)s.O)[(long long)z*s.sO + (long long)row*s.ldc + col] = v;
        }
      }
    return;
  }

  if (s.flags & 64) {
    // ================= fused Sc + row softmax =================
    const int niter = s.K >> 5;
    const int z = bid >> 2, mb = bid & 3;
    const ushort* pa = s.A + (long long)z*s.sA + (long long)(mb*64 + (t >> 2))*s.lda + (t & 3)*8;
    const ushort* pb = s.B + (long long)z*s.sB + (long long)(t >> 2)*s.ldb + (t & 3)*8;
    const long long b64 = 64ll*s.ldb;

    f32x4 acc[16] = {};
#define ISSUE_S(idx) { const int _i=(idx); const int _o=(_i&1)*20480 + lb0;      \
    const int _k=_i<<5;                                                          \
    async16(pa + _k, lds, _o);                                                   \
    async16(pb + _k,        lds, _o + 4096);                                     \
    async16(pb + b64 + _k,  lds, _o + 8192);                                     \
    async16(pb + 2*b64 + _k,lds, _o + 12288);                                    \
    async16(pb + 3*b64 + _k,lds, _o + 16384); }
    ISSUE_S(0);
    for (int i = 0; i < niter; ++i) {
      __syncthreads();
      if (i + 1 < niter) ISSUE_S(i + 1);
      const ushort* LA = lds + (i & 1)*10240;
      const ushort* LB = LA + 2048;
      const bf16x8 af = *(const bf16x8*)&LA[(wave*16 + lr)*32 + lq*8];
      #pragma unroll
      for (int j = 0; j < 16; j++) {
        const bf16x8 bfr = *(const bf16x8*)&LB[(j*16 + lr)*32 + lq*8];
        acc[j] = __builtin_amdgcn_mfma_f32_16x16x32_bf16(af, bfr, acc[j], 0, 0, 0);
      }
    }
    float mx[4] = {-1e30f, -1e30f, -1e30f, -1e30f};
    #pragma unroll
    for (int j = 0; j < 16; j++)
      #pragma unroll
      for (int r = 0; r < 4; r++) mx[r] = fmaxf(mx[r], acc[j][r]);
    #pragma unroll
    for (int r = 0; r < 4; r++)
      #pragma unroll
      for (int off = 1; off <= 8; off <<= 1) mx[r] = fmaxf(mx[r], __shfl_xor(mx[r], off, 64));
    float sm[4] = {0.f, 0.f, 0.f, 0.f};
    #pragma unroll
    for (int j = 0; j < 16; j++)
      #pragma unroll
      for (int r = 0; r < 4; r++) { float e = __expf(acc[j][r] - mx[r]); acc[j][r] = e; sm[r] += e; }
    #pragma unroll
    for (int r = 0; r < 4; r++) {
      #pragma unroll
      for (int off = 1; off <= 8; off <<= 1) sm[r] += __shfl_xor(sm[r], off, 64);
      sm[r] = 1.0f / sm[r];
    }
    ushort* Oz = (ushort*)s.O + (long long)z*s.sO;
    #pragma unroll
    for (int j = 0; j < 16; j++)
      #pragma unroll
      for (int r = 0; r < 4; r++) {
        const int row = mb*64 + wave*16 + lq*4 + r;
        Oz[(long long)row*s.ldc + j*16 + lr] = f2bf(acc[j][r]*sm[r]);
      }
    return;
  }

  // ================= plain NT GEMM, reg-direct, barrier-free =================
  {
    const int z  = bid / s.nbxy;
    const int rz = bid % s.nbxy;
    const int bx = rz % s.nbx, by = rz / s.nbx;
    const int wm = (wave >> 1)*64, wn = (wave & 1)*64;

    const ushort* pA = s.A + (long long)z*s.sA + (long long)(by*128 + wm + lr)*s.lda + lq*8;
    const ushort* pB = s.B + (long long)z*s.sB + (long long)(bx*128 + wn + lr)*s.ldb + lq*8;
    const long long a16 = 16ll*s.lda, b16 = 16ll*s.ldb;

    f32x4 acc[4][4] = {};
    #pragma unroll 4
    for (int k0 = 0; k0 < s.K; k0 += 32) {
      bf16x8 af[4], bfr[4];
      #pragma unroll
      for (int x = 0; x < 4; x++) {
        af[x]  = *(const bf16x8*)(pA + x*a16 + k0);
        bfr[x] = *(const bf16x8*)(pB + x*b16 + k0);
      }
      MFMA16(af, bfr);
    }
    const int rowb = by*128 + wm + lq*4;
    const int colb = bx*128 + wn + lr;
    const int fl = s.flags;
    #pragma unroll
    for (int x = 0; x < 4; x++)
      #pragma unroll
      for (int y = 0; y < 4; y++) {
        const int col = colb + y*16;
        #pragma unroll
        for (int r = 0; r < 4; r++) {
          const int row = rowb + x*16 + r;
          float v = acc[x][y][r];
          if (fl & 1) v = fmaxf(v, 0.f);
          if (fl & 2)
            ((ushort*)s.O)[(long long)z*s.sO + (long long)row*s.ldc + col] = f2bf(v);
          else
            ((float*)s.O)[(long long)z*s.sO + (long long)row*s.ldc + col] = v;
        }
      }
  }
}

// ---------------------------------------------------------------------------
// fused prep: [0,8192) cast f -> bf16 ; [8192,11008) 11 weight transposes ;
// [11008,15104) adj -> adj/adjT bf16
// ---------------------------------------------------------------------------
struct P11 { const float* p[11]; };

__global__ void prep(const float* __restrict__ F, ushort* __restrict__ FB,
                     P11 ps, ushort* __restrict__ WT,
                     const float* __restrict__ ADJ, ushort* __restrict__ AB,
                     ushort* __restrict__ ATB)
{
  __shared__ float tile[32][33];
  const int b = blockIdx.x, t = threadIdx.x;
  if (b < 8192) {
    const int i = b*256 + t;
    const float4 v = ((const float4*)F)[i];
    ushort4 o; o.x = f2bf(v.x); o.y = f2bf(v.y); o.z = f2bf(v.z); o.w = f2bf(v.w);
    ((ushort4*)FB)[i] = o;
  } else if (b < 11008) {
    const int q = b - 8192;
    const int wdx = q >> 8, tl = q & 255;
    const int bo = (tl & 15)*32, bk = (tl >> 4)*32;
    const int tx = t & 31, ty = t >> 5;
    const float* in = ps.p[wdx];
    ushort* o = WT + (long long)wdx*262144;
    #pragma unroll
    for (int r = 0; r < 32; r += 8) tile[ty+r][tx] = in[(long long)(bk+ty+r)*512 + bo+tx];
    __syncthreads();
    #pragma unroll
    for (int r = 0; r < 32; r += 8) o[(long long)(bo+ty+r)*512 + bk+tx] = f2bf(tile[tx][ty+r]);
  } else {
    const int q = b - 11008;
    const long long base = (long long)(q >> 6)*65536;
    const int bi = ((q >> 3) & 7)*32, bj = (q & 7)*32;
    const int tx = t & 31, ty = t >> 5;
    #pragma unroll
    for (int r = 0; r < 32; r += 8) {
      const float v = ADJ[base + (long long)(bi+ty+r)*256 + bj+tx];
      tile[ty+r][tx] = v;
      AB[base + (long long)(bi+ty+r)*256 + bj+tx] = f2bf(v);
    }
    __syncthreads();
    #pragma unroll
    for (int r = 0; r < 32; r += 8)
      ATB[base + (long long)(bj+ty+r)*256 + bi+tx] = f2bf(tile[tx][ty+r]);
  }
}

// ---------------------------------------------------------------------------
extern "C" void kernel_launch(void* const* d_in, const int* in_sizes, int n_in,
                              void* d_out, int out_size, void* d_ws, size_t ws_size,
                              hipStream_t stream)
{
  (void)in_sizes; (void)n_in; (void)out_size;
  const float* F   = (const float*)d_in[0];
  const float* ADJ = (const float*)d_in[2];

  uint8_t* w = (uint8_t*)d_ws;
  size_t off = 0;
  auto alloc = [&](size_t bytes) -> void* { void* p = w + off; off += (bytes + 255) & ~(size_t)255; return p; };

  const long long SL = 262144;
  ushort* WT   = (ushort*)alloc(11*524288);  // 0:Wst1 1:Wst1b 2:Wst2 3:Wst2b 4:Wst3 5:Wst3b 6-8:Wsim1-3 9:Wse1T 10:Wse2T
  ushort* WMT  = (ushort*)alloc(524288);
  ushort* FB   = (ushort*)alloc(16777216);
  ushort* ADJB = (ushort*)alloc(8388608);
  ushort* ADJT = (ushort*)alloc(8388608);
  ushort* TB   = (ushort*)alloc(16777216);
  ushort* Sb   = (ushort*)alloc(8388608);
  ushort* Hb   = (ushort*)alloc(16777216);   // st ping
  ushort* Hb2  = (ushort*)alloc(16777216);   // st pong
  ushort* Gb   = (ushort*)alloc(16777216);   // sim ping
  ushort* Gb2  = (ushort*)alloc(16777216);   // sim pong
  if (off > ws_size) return;

  const long long sNC = 131072, sNN = 65536;
  const int LDSB = 40960;   // max(Yt 33792, ScS staging 40960)

  auto zero = [](Seg& s) {
    s.A = nullptr; s.B = nullptr; s.Src = nullptr; s.Src2 = nullptr; s.O = nullptr;
    s.sA = s.sB = s.sS = s.sS2 = s.sO = 0;
    s.lda = s.ldb = s.ldS = s.ldS2 = s.ldc = 0;
    s.K = 0; s.nbx = 1; s.nbxy = 1; s.flags = 0; s.A2off = s.B2off = 0;
  };
  auto mkP = [&](const void* A, long long sA, int lda, const void* B, long long sB, int ldb,
                 void* O, long long sO, int ldc, int K, int M, int Nn, int flags) -> Seg {
    Seg s; zero(s);
    s.A = (const ushort*)A; s.B = (const ushort*)B; s.O = O;
    s.sA = sA; s.sB = sB; s.sO = sO;
    s.lda = lda; s.ldb = ldb; s.ldc = ldc;
    s.K = K; s.nbx = Nn/128; s.nbxy = (Nn/128)*(M/128); s.flags = flags;
    return s;
  };
  auto mkF = [&](const void* X, const void* Wf, long long B2off, const void* G, long long A2off,
                 const void* Src2, void* O, int flags) -> Seg {
    Seg s; zero(s);
    s.A = (const ushort*)X; s.sA = sNC; s.lda = 512;
    s.B = (const ushort*)Wf; s.B2off = B2off;
    s.Src = G; s.sS = sNN; s.ldS = 256; s.A2off = A2off;
    s.Src2 = Src2; s.sS2 = sNC; s.ldS2 = 512;
    s.O = O; s.sO = sNC; s.ldc = 512;
    s.flags = 128 | flags;
    return s;
  };
  auto L1 = [&](const Seg& a, int na) { mega<<<na, 256, LDSB, stream>>>(a, a, a, na, na); };
  auto L2 = [&](const Seg& a, int na, const Seg& b, int nb) {
    mega<<<na+nb, 256, LDSB, stream>>>(a, b, b, na, na+nb); };

  // ---- D1: fused prep ----
  P11 ps;
  ps.p[0] = (const float*)d_in[5];  ps.p[1] = (const float*)d_in[8];
  ps.p[2] = (const float*)d_in[6];  ps.p[3] = (const float*)d_in[9];
  ps.p[4] = (const float*)d_in[7];  ps.p[5] = (const float*)d_in[10];
  ps.p[6] = (const float*)d_in[11]; ps.p[7] = (const float*)d_in[12];
  ps.p[8] = (const float*)d_in[13];
  ps.p[9] = (const float*)d_in[3];  ps.p[10] = (const float*)d_in[4];
  prep<<<15104, 256, 0, stream>>>(F, FB, ps, WT, ADJ, ADJB, ADJT);

  const long long dA = (long long)(ADJT - ADJB);

  Seg Wmid = mkP(WT+10*SL,0,512, WT+9*SL,0,512, WMT,0,512, 512, 512,512, 2);
  Seg Tsg  = mkP(FB,sNC,512, WMT,0,512, TB,sNC,512, 512, 256,512, 2);
  Seg ScS; zero(ScS);
  ScS.A = TB; ScS.B = FB; ScS.O = Sb;
  ScS.sA = sNC; ScS.sB = sNC; ScS.sO = sNN;
  ScS.lda = 512; ScS.ldb = 512; ScS.ldc = 256;
  ScS.K = 512; ScS.flags = 64;

  Seg ST1  = mkF(FB,  WT+0*SL, SL, ADJB, dA, nullptr, Hb,  16|2);
  Seg ST2  = mkF(Hb,  WT+2*SL, SL, ADJB, dA, nullptr, Hb2, 16|2);
  Seg ST3  = mkF(Hb2, WT+4*SL, SL, ADJB, dA, nullptr, Hb,  16|2);
  Seg SIM1 = mkF(FB,  WT+6*SL, 0,  Sb,   0,  nullptr, Gb,  2);
  Seg SIM2 = mkF(Gb,  WT+7*SL, 0,  Sb,   0,  nullptr, Gb2, 2);
  Seg SIM3 = mkF(Gb2, WT+8*SL, 0,  Sb,   0,  Hb,      d_out, 4);   // fp32 out = relu(S@Y3) + Hst

  // ---- schedule: st chain || sim front-end ----
  L2(Wmid,16, ST1,512);   // D2
  L2(Tsg,512, ST2,512);   // D3
  L2(ScS,256, ST3,512);   // D4
  L1(SIM1,512);           // D5
  L1(SIM2,512);           // D6
  L1(SIM3,512);           // D7
}

// Round 4
// 388.496 us; speedup vs baseline: 1.5110x; 1.5110x over previous
//
#include <hip/hip_runtime.h>
#include <stdint.h>

#define DEVI __device__ __forceinline__

using bf16x8 = __attribute__((ext_vector_type(8))) __bf16;
using f32x4  = __attribute__((ext_vector_type(4))) float;

DEVI ushort f2bf(float f){
  uint32_t u = __float_as_uint(f);
  uint32_t r = u + 0x7fffu + ((u >> 16) & 1u);   // RNE
  return (ushort)(r >> 16);
}
DEVI float bf2f(ushort h){ return __uint_as_float(((uint32_t)h) << 16); }

// async 16B global -> LDS (wave-uniform LDS base; lane lands at base + lane*16)
DEVI void async16(const ushort* g, ushort* l, int lbyte) {
  __builtin_amdgcn_global_load_lds(
      (const __attribute__((address_space(1))) uint32_t*)g,
      (__attribute__((address_space(3))) uint32_t*)((char*)l + lbyte),
      16, 0, 0);
}

// ---------------------------------------------------------------------------
// Segmented mega kernel. Paths:
//  flags&128: FUSED GCN LAYER  out = relu(G @ (X @ Wslab)) [+ dual branch]
//             block = (z, 64-col slab); phase1 Y=X@Wslab -> LDS (transposed,
//             stride 264); phase2 G@Y with B-frags from LDS. Y never hits HBM.
//             Staging LDS double-buffered, prefetch-after-barrier (R1 timing).
//             Dual branch STRAIGHT-LINED (no runtime pass loop): pk stash has
//             a simple def/use live range -> allocator holds it in registers.
//             (R1's p-loop carried pk across a runtime back-edge -> 128B/thr
//             scratch spill, +17MB symmetric FETCH/WRITE.)
//  flags&64 : fused Sc + row softmax (LDS-staged, pipelined)
//  else     : plain NT GEMM 128x128 tile, LDS-staged, double-buffered
// flags: 1=relu 2=out_bf16 4=add Src2 bf16 16=dual 64=ScS 128=fused layer
// ---------------------------------------------------------------------------
struct Seg {
  const ushort* A; const ushort* B; const void* Src; const void* Src2; void* O;
  long long sA, sB, sS, sS2, sO;
  int lda, ldb, ldS, ldS2, ldc;
  int K, nbx, nbxy, flags;
  long long A2off, B2off;
};

__global__ __launch_bounds__(256, 2)
void mega(Seg s0, Seg s1, Seg s2, int n0s, int n01)
{
  extern __shared__ __align__(16) ushort lds[];
  int bid = blockIdx.x;
  const Seg& s = (bid < n0s) ? s0 : ((bid < n01) ? s1 : s2);
  if (bid >= n0s) bid -= (bid < n01) ? n0s : n01;

  const int t = threadIdx.x;
  const int lane = t & 63, wave = t >> 6;
  const int lr = lane & 15, lq = lane >> 4;
  const int lb0 = __builtin_amdgcn_readfirstlane((t & 192) * 16);

#define MFMA16(Aa, Bb) { _Pragma("unroll") for (int x = 0; x < 4; x++)           \
    _Pragma("unroll") for (int y = 0; y < 4; y++)                                \
      acc[x][y] = __builtin_amdgcn_mfma_f32_16x16x32_bf16(Aa[x], Bb[y], acc[x][y], 0, 0, 0); }

  if (s.flags & 128) {
    // ================= fused GCN layer =================
    const int z    = (bid & 7) + ((bid >> 6) << 3);   // XCD swizzle: same z -> same XCD
    const int slab = (bid >> 3) & 7;
    const int n0   = slab * 64;

    // LDS map (bytes):
    //   [0, 33792)              Yt: 64 cols x 264 (256 rows + pad), bf16
    //   [33792 + b*20480, ...)  staging buf b: stA 256x32 (16384B) + stW 64x32 (4096B)
    ushort* Yt = lds;

    const int r0 = t >> 2, c0 = (t & 3) * 8;

    const ushort* X  = s.A + (long long)z * s.sA;
    const ushort* Wf = s.B + (long long)n0 * 512;
    const ushort* G0 = (const ushort*)s.Src + (long long)z * s.sS;

    f32x4 acc[4][4] = {};

#define COMPUTE1(curb) {                                                         \
      const ushort* sA = (const ushort*)((const char*)lds + 33792 + (curb)*20480); \
      const ushort* sW = sA + 8192;                                              \
      bf16x8 af[4], bw[4];                                                       \
      _Pragma("unroll") for (int x = 0; x < 4; x++)                              \
        af[x] = *(const bf16x8*)&sA[(64*wave + x*16 + lr)*32 + lq*8];            \
      _Pragma("unroll") for (int y = 0; y < 4; y++)                              \
        bw[y] = *(const bf16x8*)&sW[(y*16 + lr)*32 + lq*8];                      \
      MFMA16(af, bw); }

#define COMPUTE2(curb, kk) {                                                     \
      const ushort* sA = (const ushort*)((const char*)lds + 33792 + (curb)*20480); \
      bf16x8 af[4], bfr[4];                                                      \
      _Pragma("unroll") for (int x = 0; x < 4; x++)                              \
        af[x] = *(const bf16x8*)&sA[(64*wave + x*16 + lr)*32 + lq*8];            \
      _Pragma("unroll") for (int y = 0; y < 4; y++)                              \
        bfr[y] = *(const bf16x8*)&Yt[(y*16 + lr)*264 + (kk) + lq*8];             \
      MFMA16(af, bfr); }

#define ISSUE1(k0s, b) { const int _o = 33792 + (b)*20480 + lb0;                 \
      _Pragma("unroll") for (int i = 0; i < 4; i++)                              \
        async16(pX + (long long)(64*i)*512 + (k0s), lds, _o + i*4096);           \
      async16(pW + (k0s), lds, _o + 16384); }

#define ISSUE2(k0s, b) { const int _o = 33792 + (b)*20480 + lb0;                 \
      _Pragma("unroll") for (int i = 0; i < 4; i++)                              \
        async16(pG + (long long)(64*i)*s.ldS + (k0s), lds, _o + i*4096); }

    // one full (ph1 -> Yt -> ph2) pass; result accumulates into acc
#define PASS(Wptr, Gptr) {                                                       \
      const ushort* pX = X + (long long)r0*512 + c0;                             \
      const ushort* pW = (Wptr) + (long long)r0*512 + c0;                        \
      __syncthreads();                 /* prior staging/Yt reads complete */     \
      ISSUE1(0, 0);                                                              \
      for (int k0 = 0; k0 < 480; k0 += 32) {                                     \
        const int cur = (k0 >> 5) & 1;                                           \
        __syncthreads();               /* buf cur ready */                       \
        ISSUE1(k0 + 32, cur ^ 1);      /* flies under MFMA below */              \
        COMPUTE1(cur);                                                           \
      }                                                                          \
      __syncthreads();                                                           \
      COMPUTE1(1);                     /* k0=480 landed in buf 1 */              \
      _Pragma("unroll") for (int x = 0; x < 4; x++)                              \
        _Pragma("unroll") for (int y = 0; y < 4; y++) {                          \
          const int col  = y*16 + lr;                                            \
          const int rowb = 64*wave + x*16 + lq*4;                                \
          uint2 vv;                                                              \
          vv.x = (uint)f2bf(acc[x][y][0]) | ((uint)f2bf(acc[x][y][1]) << 16);    \
          vv.y = (uint)f2bf(acc[x][y][2]) | ((uint)f2bf(acc[x][y][3]) << 16);    \
          *(uint2*)&Yt[col*264 + rowb] = vv;                                     \
          acc[x][y] = (f32x4){0.f, 0.f, 0.f, 0.f};                               \
        }                                                                        \
      const ushort* pG = (Gptr) + (long long)r0 * s.ldS + c0;                    \
      __syncthreads();                 /* Yt visible; ph1 stA reads done */      \
      ISSUE2(0, 0);                                                              \
      for (int k0 = 0; k0 < 224; k0 += 32) {                                     \
        const int cur = (k0 >> 5) & 1;                                           \
        __syncthreads();                                                         \
        ISSUE2(k0 + 32, cur ^ 1);                                                \
        COMPUTE2(cur, k0);                                                       \
      }                                                                          \
      __syncthreads();                                                           \
      COMPUTE2(1, 224);                                                          \
    }

#define EPILOG(PKADD) {                                                          \
      const int fl = s.flags;                                                    \
      _Pragma("unroll") for (int x = 0; x < 4; x++)                              \
        _Pragma("unroll") for (int y = 0; y < 4; y++) {                          \
          const int col = n0 + y*16 + lr;                                        \
          _Pragma("unroll") for (int r = 0; r < 4; r++) {                        \
            const int row = 64*wave + x*16 + lq*4 + r;                           \
            float v = fmaxf(acc[x][y][r], 0.f);                                  \
            PKADD;                                                               \
            if (fl & 4)  v += bf2f(((const ushort*)s.Src2)[(long long)z*s.sS2 + (long long)row*s.ldS2 + col]); \
            if (fl & 2)                                                          \
              ((ushort*)s.O)[(long long)z*s.sO + (long long)row*s.ldc + col] = f2bf(v); \
            else                                                                 \
              ((float*)s.O)[(long long)z*s.sO + (long long)row*s.ldc + col] = v; \
          } } }

    if (s.flags & 16) {
      // -------- dual branch, straight-lined --------
      uint pk[4][4][2];
      PASS(Wf, G0);
      #pragma unroll
      for (int x = 0; x < 4; x++)
        #pragma unroll
        for (int y = 0; y < 4; y++) {
          pk[x][y][0] = (uint)f2bf(fmaxf(acc[x][y][0],0.f)) | ((uint)f2bf(fmaxf(acc[x][y][1],0.f)) << 16);
          pk[x][y][1] = (uint)f2bf(fmaxf(acc[x][y][2],0.f)) | ((uint)f2bf(fmaxf(acc[x][y][3],0.f)) << 16);
          acc[x][y] = (f32x4){0.f, 0.f, 0.f, 0.f};
        }
      PASS(Wf + s.B2off, G0 + s.A2off);
      EPILOG(v += bf2f((ushort)(pk[x][y][r >> 1] >> (16*(r & 1)))));
    } else {
      // -------- single branch --------
      PASS(Wf, G0);
      EPILOG(;);
    }
    return;
  }

  if (s.flags & 64) {
    // ================= fused Sc + row softmax =================
    const int niter = s.K >> 5;
    const int z = bid >> 2, mb = bid & 3;
    const ushort* pa = s.A + (long long)z*s.sA + (long long)(mb*64 + (t >> 2))*s.lda + (t & 3)*8;
    const ushort* pb = s.B + (long long)z*s.sB + (long long)(t >> 2)*s.ldb + (t & 3)*8;
    const long long b64 = 64ll*s.ldb;

    f32x4 acc[16] = {};
#define ISSUE_S(idx) { const int _i=(idx); const int _o=(_i&1)*20480 + lb0;      \
    const int _k=_i<<5;                                                          \
    async16(pa + _k, lds, _o);                                                   \
    async16(pb + _k,        lds, _o + 4096);                                     \
    async16(pb + b64 + _k,  lds, _o + 8192);                                     \
    async16(pb + 2*b64 + _k,lds, _o + 12288);                                    \
    async16(pb + 3*b64 + _k,lds, _o + 16384); }
    ISSUE_S(0);
    for (int i = 0; i < niter; ++i) {
      __syncthreads();
      if (i + 1 < niter) ISSUE_S(i + 1);
      const ushort* LA = lds + (i & 1)*10240;
      const ushort* LB = LA + 2048;
      const bf16x8 af = *(const bf16x8*)&LA[(wave*16 + lr)*32 + lq*8];
      #pragma unroll
      for (int j = 0; j < 16; j++) {
        const bf16x8 bfr = *(const bf16x8*)&LB[(j*16 + lr)*32 + lq*8];
        acc[j] = __builtin_amdgcn_mfma_f32_16x16x32_bf16(af, bfr, acc[j], 0, 0, 0);
      }
    }
    float mx[4] = {-1e30f, -1e30f, -1e30f, -1e30f};
    #pragma unroll
    for (int j = 0; j < 16; j++)
      #pragma unroll
      for (int r = 0; r < 4; r++) mx[r] = fmaxf(mx[r], acc[j][r]);
    #pragma unroll
    for (int r = 0; r < 4; r++)
      #pragma unroll
      for (int off = 1; off <= 8; off <<= 1) mx[r] = fmaxf(mx[r], __shfl_xor(mx[r], off, 64));
    float sm[4] = {0.f, 0.f, 0.f, 0.f};
    #pragma unroll
    for (int j = 0; j < 16; j++)
      #pragma unroll
      for (int r = 0; r < 4; r++) { float e = __expf(acc[j][r] - mx[r]); acc[j][r] = e; sm[r] += e; }
    #pragma unroll
    for (int r = 0; r < 4; r++) {
      #pragma unroll
      for (int off = 1; off <= 8; off <<= 1) sm[r] += __shfl_xor(sm[r], off, 64);
      sm[r] = 1.0f / sm[r];
    }
    ushort* Oz = (ushort*)s.O + (long long)z*s.sO;
    #pragma unroll
    for (int j = 0; j < 16; j++)
      #pragma unroll
      for (int r = 0; r < 4; r++) {
        const int row = mb*64 + wave*16 + lq*4 + r;
        Oz[(long long)row*s.ldc + j*16 + lr] = f2bf(acc[j][r]*sm[r]);
      }
    return;
  }

  // ================= plain NT GEMM, double-buffered =================
  {
    // buf b (bytes): lA 128x32 at b*16384, lB 128x32 at b*16384 + 8192
    const int z  = bid / s.nbxy;
    const int rz = bid % s.nbxy;
    const int bx = rz % s.nbx, by = rz / s.nbx;
    const int wm = (wave >> 1)*64, wn = (wave & 1)*64;
    const int r0 = t >> 2, c0 = (t & 3)*8;

    const ushort* pa = s.A + (long long)z*s.sA + (long long)(by*128 + r0)*s.lda + c0;
    const ushort* pb = s.B + (long long)z*s.sB + (long long)(bx*128 + r0)*s.ldb + c0;
    const long long a64 = 64ll*s.lda, b64 = 64ll*s.ldb;

#define ISSUEP(k0s, b) { const int _o = (b)*16384 + lb0;                         \
      async16(pa + (k0s),       lds, _o);                                        \
      async16(pa + a64 + (k0s), lds, _o + 4096);                                 \
      async16(pb + (k0s),       lds, _o + 8192);                                 \
      async16(pb + b64 + (k0s), lds, _o + 12288); }

#define COMPUTEP(curb) {                                                         \
      const ushort* lA = (const ushort*)((const char*)lds + (curb)*16384);       \
      const ushort* lB = lA + 4096;                                              \
      bf16x8 af[4], bfr[4];                                                      \
      _Pragma("unroll") for (int x = 0; x < 4; x++) {                            \
        af[x]  = *(const bf16x8*)&lA[(wm + x*16 + lr)*32 + lq*8];                \
        bfr[x] = *(const bf16x8*)&lB[(wn + x*16 + lr)*32 + lq*8];                \
      }                                                                          \
      MFMA16(af, bfr); }

    f32x4 acc[4][4] = {};
    ISSUEP(0, 0);
    int k0 = 0;
    for (; k0 < s.K - 32; k0 += 32) {
      const int cur = (k0 >> 5) & 1;
      __syncthreads();                 // buf cur ready
      ISSUEP(k0 + 32, cur ^ 1);
      COMPUTEP(cur);
    }
    __syncthreads();
    COMPUTEP((k0 >> 5) & 1);
    const int rowb = by*128 + wm + lq*4;
    const int colb = bx*128 + wn + lr;
    const int fl = s.flags;
    #pragma unroll
    for (int x = 0; x < 4; x++)
      #pragma unroll
      for (int y = 0; y < 4; y++) {
        const int col = colb + y*16;
        #pragma unroll
        for (int r = 0; r < 4; r++) {
          const int row = rowb + x*16 + r;
          float v = acc[x][y][r];
          if (fl & 1) v = fmaxf(v, 0.f);
          if (fl & 2)
            ((ushort*)s.O)[(long long)z*s.sO + (long long)row*s.ldc + col] = f2bf(v);
          else
            ((float*)s.O)[(long long)z*s.sO + (long long)row*s.ldc + col] = v;
        }
      }
  }
}

// ---------------------------------------------------------------------------
// fused prep: [0,8192) cast f -> bf16 ; [8192,11008) 11 weight transposes ;
// [11008,15104) adj -> adj/adjT bf16
// ---------------------------------------------------------------------------
struct P11 { const float* p[11]; };

__global__ void prep(const float* __restrict__ F, ushort* __restrict__ FB,
                     P11 ps, ushort* __restrict__ WT,
                     const float* __restrict__ ADJ, ushort* __restrict__ AB,
                     ushort* __restrict__ ATB)
{
  __shared__ float tile[32][33];
  const int b = blockIdx.x, t = threadIdx.x;
  if (b < 8192) {
    const int i = b*256 + t;
    const float4 v = ((const float4*)F)[i];
    ushort4 o; o.x = f2bf(v.x); o.y = f2bf(v.y); o.z = f2bf(v.z); o.w = f2bf(v.w);
    ((ushort4*)FB)[i] = o;
  } else if (b < 11008) {
    const int q = b - 8192;
    const int wdx = q >> 8, tl = q & 255;
    const int bo = (tl & 15)*32, bk = (tl >> 4)*32;
    const int tx = t & 31, ty = t >> 5;
    const float* in = ps.p[wdx];
    ushort* o = WT + (long long)wdx*262144;
    #pragma unroll
    for (int r = 0; r < 32; r += 8) tile[ty+r][tx] = in[(long long)(bk+ty+r)*512 + bo+tx];
    __syncthreads();
    #pragma unroll
    for (int r = 0; r < 32; r += 8) o[(long long)(bo+ty+r)*512 + bk+tx] = f2bf(tile[tx][ty+r]);
  } else {
    const int q = b - 11008;
    const long long base = (long long)(q >> 6)*65536;
    const int bi = ((q >> 3) & 7)*32, bj = (q & 7)*32;
    const int tx = t & 31, ty = t >> 5;
    #pragma unroll
    for (int r = 0; r < 32; r += 8) {
      const float v = ADJ[base + (long long)(bi+ty+r)*256 + bj+tx];
      tile[ty+r][tx] = v;
      AB[base + (long long)(bi+ty+r)*256 + bj+tx] = f2bf(v);
    }
    __syncthreads();
    #pragma unroll
    for (int r = 0; r < 32; r += 8)
      ATB[base + (long long)(bj+ty+r)*256 + bi+tx] = f2bf(tile[tx][ty+r]);
  }
}

// ---------------------------------------------------------------------------
extern "C" void kernel_launch(void* const* d_in, const int* in_sizes, int n_in,
                              void* d_out, int out_size, void* d_ws, size_t ws_size,
                              hipStream_t stream)
{
  (void)in_sizes; (void)n_in; (void)out_size;
  const float* F   = (const float*)d_in[0];
  const float* ADJ = (const float*)d_in[2];

  uint8_t* w = (uint8_t*)d_ws;
  size_t off = 0;
  auto alloc = [&](size_t bytes) -> void* { void* p = w + off; off += (bytes + 255) & ~(size_t)255; return p; };

  const long long SL = 262144;
  ushort* WT   = (ushort*)alloc(11*524288);  // 0:Wst1 1:Wst1b 2:Wst2 3:Wst2b 4:Wst3 5:Wst3b 6-8:Wsim1-3 9:Wse1T 10:Wse2T
  ushort* WMT  = (ushort*)alloc(524288);
  ushort* FB   = (ushort*)alloc(16777216);
  ushort* ADJB = (ushort*)alloc(8388608);
  ushort* ADJT = (ushort*)alloc(8388608);
  ushort* TB   = (ushort*)alloc(16777216);
  ushort* Sb   = (ushort*)alloc(8388608);
  ushort* Hb   = (ushort*)alloc(16777216);   // st ping
  ushort* Hb2  = (ushort*)alloc(16777216);   // st pong
  ushort* Gb   = (ushort*)alloc(16777216);   // sim ping
  ushort* Gb2  = (ushort*)alloc(16777216);   // sim pong
  if (off > ws_size) return;

  const long long sNC = 131072, sNN = 65536;
  const int LDSB = 74752;   // Yt 33792 + 2x(16384+4096) staging dbuf

  auto zero = [](Seg& s) {
    s.A = nullptr; s.B = nullptr; s.Src = nullptr; s.Src2 = nullptr; s.O = nullptr;
    s.sA = s.sB = s.sS = s.sS2 = s.sO = 0;
    s.lda = s.ldb = s.ldS = s.ldS2 = s.ldc = 0;
    s.K = 0; s.nbx = 1; s.nbxy = 1; s.flags = 0; s.A2off = s.B2off = 0;
  };
  auto mkP = [&](const void* A, long long sA, int lda, const void* B, long long sB, int ldb,
                 void* O, long long sO, int ldc, int K, int M, int Nn, int flags) -> Seg {
    Seg s; zero(s);
    s.A = (const ushort*)A; s.B = (const ushort*)B; s.O = O;
    s.sA = sA; s.sB = sB; s.sO = sO;
    s.lda = lda; s.ldb = ldb; s.ldc = ldc;
    s.K = K; s.nbx = Nn/128; s.nbxy = (Nn/128)*(M/128); s.flags = flags;
    return s;
  };
  auto mkF = [&](const void* X, const void* Wf, long long B2off, const void* G, long long A2off,
                 const void* Src2, void* O, int flags) -> Seg {
    Seg s; zero(s);
    s.A = (const ushort*)X; s.sA = sNC; s.lda = 512;
    s.B = (const ushort*)Wf; s.B2off = B2off;
    s.Src = G; s.sS = sNN; s.ldS = 256; s.A2off = A2off;
    s.Src2 = Src2; s.sS2 = sNC; s.ldS2 = 512;
    s.O = O; s.sO = sNC; s.ldc = 512;
    s.flags = 128 | flags;
    return s;
  };
  auto L1 = [&](const Seg& a, int na) { mega<<<na, 256, LDSB, stream>>>(a, a, a, na, na); };
  auto L2 = [&](const Seg& a, int na, const Seg& b, int nb) {
    mega<<<na+nb, 256, LDSB, stream>>>(a, b, b, na, na+nb); };

  // ---- D1: fused prep ----
  P11 ps;
  ps.p[0] = (const float*)d_in[5];  ps.p[1] = (const float*)d_in[8];
  ps.p[2] = (const float*)d_in[6];  ps.p[3] = (const float*)d_in[9];
  ps.p[4] = (const float*)d_in[7];  ps.p[5] = (const float*)d_in[10];
  ps.p[6] = (const float*)d_in[11]; ps.p[7] = (const float*)d_in[12];
  ps.p[8] = (const float*)d_in[13];
  ps.p[9] = (const float*)d_in[3];  ps.p[10] = (const float*)d_in[4];
  prep<<<15104, 256, 0, stream>>>(F, FB, ps, WT, ADJ, ADJB, ADJT);

  const long long dA = (long long)(ADJT - ADJB);

  Seg Wmid = mkP(WT+10*SL,0,512, WT+9*SL,0,512, WMT,0,512, 512, 512,512, 2);
  Seg Tsg  = mkP(FB,sNC,512, WMT,0,512, TB,sNC,512, 512, 256,512, 2);
  Seg ScS; zero(ScS);
  ScS.A = TB; ScS.B = FB; ScS.O = Sb;
  ScS.sA = sNC; ScS.sB = sNC; ScS.sO = sNN;
  ScS.lda = 512; ScS.ldb = 512; ScS.ldc = 256;
  ScS.K = 512; ScS.flags = 64;

  Seg ST1  = mkF(FB,  WT+0*SL, SL, ADJB, dA, nullptr, Hb,  16|2);
  Seg ST2  = mkF(Hb,  WT+2*SL, SL, ADJB, dA, nullptr, Hb2, 16|2);
  Seg ST3  = mkF(Hb2, WT+4*SL, SL, ADJB, dA, nullptr, Hb,  16|2);
  Seg SIM1 = mkF(FB,  WT+6*SL, 0,  Sb,   0,  nullptr, Gb,  2);
  Seg SIM2 = mkF(Gb,  WT+7*SL, 0,  Sb,   0,  nullptr, Gb2, 2);
  Seg SIM3 = mkF(Gb2, WT+8*SL, 0,  Sb,   0,  Hb,      d_out, 4);   // fp32 out = relu(S@Y3) + Hst

  // ---- schedule: st chain || sim front-end ----
  L2(Wmid,16, ST1,512);   // D2
  L2(Tsg,512, ST2,512);   // D3
  L2(ScS,256, ST3,512);   // D4
  L1(SIM1,512);           // D5
  L1(SIM2,512);           // D6
  L1(SIM3,512);           // D7
}